// Round 16
// baseline (2543.486 us; speedup 1.0000x reference)
//
#include <hip/hip_runtime.h>

#define HIDDEN 512
#define TSEQ 512
#define NKEYS 128

typedef short short8_t __attribute__((ext_vector_type(8)));
typedef short short4_t __attribute__((ext_vector_type(4)));
typedef float f32x4 __attribute__((ext_vector_type(4)));
typedef int i32x4 __attribute__((ext_vector_type(4)));
typedef int i32x2 __attribute__((ext_vector_type(2)));

__device__ __forceinline__ ushort f2bf(float f) {
    union { float f; unsigned u; } v; v.f = f;
    unsigned r = (v.u + 0x7FFFu + ((v.u >> 16) & 1u)) >> 16;
    return (ushort)r;
}
__device__ __forceinline__ float sigm(float x) { return 1.0f / (1.0f + __expf(-x)); }
__device__ __forceinline__ float tanh_f(float x) { return 2.0f / (1.0f + __expf(-2.0f * x)) - 1.0f; }

// Plain row-major bf16 cast of [W_ih | W_hh]: Wc[row*K + k].
__global__ void cast_w(const float* __restrict__ Wih, const float* __restrict__ Whh,
                       ushort* __restrict__ Wc, int KIN, int K) {
    long idx = (long)blockIdx.x * blockDim.x + threadIdx.x;
    if (idx >= (long)2048 * K) return;
    int row = (int)(idx / K), k = (int)(idx % K);
    float v = (k < KIN) ? Wih[(long)row * KIN + k] : Whh[(long)row * HIDDEN + (k - KIN)];
    Wc[idx] = f2bf(v);
}

__global__ void prep_bias(const float* __restrict__ a, const float* __restrict__ b,
                          const float* __restrict__ c, const float* __restrict__ d,
                          float* __restrict__ b0, float* __restrict__ b1) {
    int i = blockIdx.x * blockDim.x + threadIdx.x;
    if (i < 2048) { b0[i] = a[i] + b[i]; b1[i] = c[i] + d[i]; }
}

// Zero h0s slot 0 (h0(-1)) and h1p parity 0 (h1(-1)); both are 131072 ushorts.
__global__ void init_zeros(ushort* __restrict__ h0s, ushort* __restrict__ h1p) {
    int idx = blockIdx.x * blockDim.x + threadIdx.x;   // 65536 threads, ushort4 each
    ushort4 z = {0, 0, 0, 0};
    if (idx < 32768) *(ushort4*)(h0s + (size_t)idx * 4) = z;
    else             *(ushort4*)(h1p + (size_t)(idx - 32768) * 4) = z;
}

// ---- named weight registers, pinned into AGPRs ----
#define AF_LIST_20(M) M(0)M(1)M(2)M(3)M(4)M(5)M(6)M(7)M(8)M(9)M(10)M(11)M(12)M(13)M(14)M(15)M(16)M(17)M(18)M(19)
#define AF_LIST_32(M) AF_LIST_20(M) M(20)M(21)M(22)M(23)M(24)M(25)M(26)M(27)M(28)M(29)M(30)M(31)

#define AF_DECL(i) short8_t af##i;
#define AF_LOAD(i) af##i = *(const short8_t*)(wsrc + (i) * 32); \
                   asm volatile("" : "+a"(af##i));

// Two M-subtiles (batch rows arow and 16+arow) share each weight fragment.
#define AF_MFMA(i) { \
    const char* _b  = ((i) < KSI) ? (bpi + (i) * 64) : (bpr + ((i) - KSI) * 64); \
    const int   _r16 = ((i) < KSI) ? (16 * INROW) : (16 * RECROW); \
    short8_t bf0 = *(const short8_t*)_b; \
    short8_t bf1 = *(const short8_t*)(_b + _r16); \
    if ((i) & 1) { \
        asm("v_mfma_f32_16x16x32_bf16 %0, %1, %2, %0" : "+v"(accA1) : "a"(af##i), "v"(bf0)); \
        asm("v_mfma_f32_16x16x32_bf16 %0, %1, %2, %0" : "+v"(accB1) : "a"(af##i), "v"(bf1)); \
    } else { \
        asm("v_mfma_f32_16x16x32_bf16 %0, %1, %2, %0" : "+v"(accA0) : "a"(af##i), "v"(bf0)); \
        asm("v_mfma_f32_16x16x32_bf16 %0, %1, %2, %0" : "+v"(accB0) : "a"(af##i), "v"(bf1)); \
    } }

// scatter one 16B reg (2 rows x 4 units) into LDS [row][unit] layout
#define SCAT2(base, stride, uo, r0_, REG) { \
    i32x2 _lo, _hi; _lo[0] = REG[0]; _lo[1] = REG[1]; _hi[0] = REG[2]; _hi[1] = REG[3]; \
    *(i32x2*)((base) + (r0_) * (stride) + (uo)) = _lo; \
    *(i32x2*)((base) + ((r0_) + 1) * (stride) + (uo)) = _hi; }

// Fused 2-layer LSTM, layer-pipelined, XCD-local. Round-16 changes (publish leg):
//  (a) WAVE-MAJOR chunks [8 wv][32 rows][4 units]: each wave's shfl-packed 8B
//      pieces are contiguous -> publish = two coalesced 128B segments per wave.
//      (r15: each 64B line assembled from 8 waves' 8B stores -> WRITE 1053MB,
//      slow partial-line drain on the critical path.)
//  (b) PER-WAVE flags: wave drains its own stores (vmcnt(0)) then stores its
//      own flag — NO barrier before flag. Consumers poll flag(pub,wv)
//      per-thread (tid = pub*32 + wv*4 + qt) and early-load that wave's 64B
//      sub-slab as soon as its flag lands.
//  (c) inb double-buffered by parity -> B_f deleted; ONE barrier per step
//      (B_s). Hazard audit: inb/rb accesses are parity-disjoint or B_s-ordered;
//      h1p ring overwrite at t+2 is ordered behind consumers' flags(t+1),
//      which are stored only after their staged reads completed.
template <int L>
__device__ __forceinline__ void lstm_body(
    char* smem, int bid,
    const float* __restrict__ x, const ushort* __restrict__ Wc,
    const float* __restrict__ biasc, ushort* __restrict__ h0s,
    ushort* __restrict__ h1p, float* __restrict__ hlast, int* flags)
{
    constexpr int KIN   = L ? 512 : 128;
    constexpr int K     = KIN + 512;
    constexpr int KSI   = KIN / 32;          // input-half k-steps (4 / 16)
    constexpr int INROW = L ? 1056 : 288;    // inb row stride (bytes), == 32 mod 128
    constexpr int RECROW = 1056;             // recb row stride (bytes)
    constexpr int RECPAR = 32 * RECROW;      // 33792 B per parity
    constexpr int INPAR  = 32 * INROW;
    constexpr size_t TSTR = 128 * 1024;      // h0s t-slot stride (ushorts)

    char* const recb = smem;                 // 2 parities x 32 rows
    char* const inb  = smem + 2 * RECPAR;    // 2 parities x 32 rows

    const int tid = threadIdx.x;
    const int tile = bid & 7;                // tile == XCD (bid%8 mapping)
    const int g    = (bid >> 3) & 15;
    const int b0   = tile * 32;
    const int w = tid >> 6, lane = tid & 63, hi4 = lane >> 4, arow = lane & 15;
    const int Uw = g * 32 + w * 4;
    const int row_l = 512 * (arow & 3) + Uw + (arow >> 2);

    // consumer roles: thread <-> (producer pub, producer wave wv, row-quarter qt)
    const int cpub = tid >> 5, cwv = (tid >> 2) & 7, cqt = tid & 3;
    const int uoff = (cpub * 32 + cwv * 4) * 2;      // byte offset in LDS row
    const bool notown = (cpub != g);

    int* const flagL = flags + (L ? 32768 : 0) + tile * 4096;  // own layer: 128 slots x 128B
    int* const flagP = flags + tile * 4096;                     // L0 flags (for L1 input)
    const unsigned long long rflagA = (unsigned long long)(flagL + (cpub * 8 + cwv) * 32);
    const unsigned long long iflagA = (unsigned long long)(flagP + (cpub * 8 + cwv) * 32);
    const unsigned long long myflagA = (unsigned long long)(flagL + (g * 8 + w) * 32);

    // ---- weights -> AGPRs (once) ----
    AF_LIST_32(AF_DECL)
    {
        const ushort* wsrc = Wc + (size_t)row_l * K + hi4 * 8;
        if constexpr (L == 0) { AF_LIST_20(AF_LOAD) }
        else                  { AF_LIST_32(AF_LOAD) }
    }
    f32x4 bias4;
#pragma unroll
    for (int r = 0; r < 4; ++r) bias4[r] = biasc[512 * r + Uw + hi4];

    // zero recb (own chunk of parity 0 must be 0 = h(-1))
    for (int i = tid; i < 2 * RECPAR / 4; i += 512) ((int*)recb)[i] = 0;

    float c0 = 0.0f, c1 = 0.0f;

    // x prefetch registers (L0): row si, 8 floats at sj*8
    const int si = tid >> 4, sj = tid & 15;
    float4 xa, xb;
    if constexpr (L == 0) {
        const float* xp = x + ((size_t)(b0 + si) * TSEQ) * NKEYS + sj * 8;
        xa = *(const float4*)xp; xb = *(const float4*)(xp + 4);
    }

    __syncthreads();   // recb zeroed

#pragma unroll 1
    for (int t = 0; t < TSEQ; ++t) {
        const int par = t & 1;
        char* const rb_cur = recb + par * RECPAR;
        char* const rb_nxt = recb + (par ^ 1) * RECPAR;
        char* const in_cur = inb + par * INPAR;

        // ---- x input -> in_cur (L0; parity-dbuf: no race with MFMA(t-1)) ----
        if constexpr (L == 0) {
            short8_t s;
            s[0] = (short)f2bf(xa.x); s[1] = (short)f2bf(xa.y);
            s[2] = (short)f2bf(xa.z); s[3] = (short)f2bf(xa.w);
            s[4] = (short)f2bf(xb.x); s[5] = (short)f2bf(xb.y);
            s[6] = (short)f2bf(xb.z); s[7] = (short)f2bf(xb.w);
            *(short8_t*)(in_cur + si * INROW + sj * 16) = s;
        }

        // ---- per-thread poll + early-load of (pub,wv) sub-slabs ----
        i32x4 ia0, ia1, ia2, ia3, rr0, rr1, rr2, rr3;
        {
            int ipend = (L == 1) ? 1 : 0;
            int rpend = notown ? 1 : 0;
            while (true) {
                if (ipend) {   // L1 input: h0(t) = slot t+1, write-once -> plain
                    int v;
                    asm volatile("global_load_dword %0, %1, off sc0 sc1\n\t"
                                 "s_waitcnt vmcnt(0)"
                                 : "=&v"(v) : "v"(iflagA) : "memory");
                    if (v >= t + 1) {
                        const ushort* p = h0s + ((size_t)(t + 1)) * TSTR
                                          + ((size_t)tile * 16 + cpub) * 1024
                                          + cwv * 128 + cqt * 32;
                        asm volatile("global_load_dwordx4 %0, %4, off\n\t"
                                     "global_load_dwordx4 %1, %5, off\n\t"
                                     "global_load_dwordx4 %2, %6, off\n\t"
                                     "global_load_dwordx4 %3, %7, off"
                                     : "=&v"(ia0), "=&v"(ia1), "=&v"(ia2), "=&v"(ia3)
                                     : "v"((unsigned long long)p),
                                       "v"((unsigned long long)(p + 8)),
                                       "v"((unsigned long long)(p + 16)),
                                       "v"((unsigned long long)(p + 24))
                                     : "memory");
                        ipend = 0;
                    }
                }
                if (rpend) {   // recurrent h(t-1) from tile-mates
                    int v;
                    asm volatile("global_load_dword %0, %1, off sc0 sc1\n\t"
                                 "s_waitcnt vmcnt(0)"
                                 : "=&v"(v) : "v"(rflagA) : "memory");
                    if (v >= t) {
                        if constexpr (L == 0) {
                            const ushort* p = h0s + ((size_t)t) * TSTR
                                              + ((size_t)tile * 16 + cpub) * 1024
                                              + cwv * 128 + cqt * 32;
                            asm volatile("global_load_dwordx4 %0, %4, off\n\t"
                                         "global_load_dwordx4 %1, %5, off\n\t"
                                         "global_load_dwordx4 %2, %6, off\n\t"
                                         "global_load_dwordx4 %3, %7, off"
                                         : "=&v"(rr0), "=&v"(rr1), "=&v"(rr2), "=&v"(rr3)
                                         : "v"((unsigned long long)p),
                                           "v"((unsigned long long)(p + 8)),
                                           "v"((unsigned long long)(p + 16)),
                                           "v"((unsigned long long)(p + 24))
                                         : "memory");
                        } else {
                            const ushort* p = h1p + (((size_t)par * 8 + tile) * 16 + cpub) * 1024
                                              + cwv * 128 + cqt * 32;
                            asm volatile("global_load_dwordx4 %0, %4, off sc0 sc1\n\t"
                                         "global_load_dwordx4 %1, %5, off sc0 sc1\n\t"
                                         "global_load_dwordx4 %2, %6, off sc0 sc1\n\t"
                                         "global_load_dwordx4 %3, %7, off sc0 sc1"
                                         : "=&v"(rr0), "=&v"(rr1), "=&v"(rr2), "=&v"(rr3)
                                         : "v"((unsigned long long)p),
                                           "v"((unsigned long long)(p + 8)),
                                           "v"((unsigned long long)(p + 16)),
                                           "v"((unsigned long long)(p + 24))
                                         : "memory");
                        }
                        rpend = 0;
                    }
                }
                if (__all((ipend | rpend) == 0)) break;
                __builtin_amdgcn_s_sleep(1);
            }
            asm volatile("s_waitcnt vmcnt(0)" ::: "memory");
            const int r0_ = cqt * 8;
            if constexpr (L == 1) {
                SCAT2(in_cur, INROW, uoff, r0_ + 0, ia0)
                SCAT2(in_cur, INROW, uoff, r0_ + 2, ia1)
                SCAT2(in_cur, INROW, uoff, r0_ + 4, ia2)
                SCAT2(in_cur, INROW, uoff, r0_ + 6, ia3)
            }
            if (notown) {
                SCAT2(rb_cur, RECROW, uoff, r0_ + 0, rr0)
                SCAT2(rb_cur, RECROW, uoff, r0_ + 2, rr1)
                SCAT2(rb_cur, RECROW, uoff, r0_ + 4, rr2)
                SCAT2(rb_cur, RECROW, uoff, r0_ + 6, rr3)
            }
        }
        // x prefetch for t+1 (cached path; consumed next step)
        if constexpr (L == 0) {
            const int tt = (t + 1) & 511;
            const float* xp = x + ((size_t)(b0 + si) * TSEQ + tt) * NKEYS + sj * 8;
            xa = *(const float4*)xp; xb = *(const float4*)(xp + 4);
        }
        __syncthreads();   // B_s: the ONE barrier per step

        // ---- MFMA sweep (A from AGPR, B from LDS; 2 subtiles x 2 chains) ----
        f32x4 accA0 = bias4, accB0 = bias4;
        f32x4 accA1 = {0.f, 0.f, 0.f, 0.f}, accB1 = {0.f, 0.f, 0.f, 0.f};
        const char* bpi = in_cur + arow * INROW + hi4 * 16;
        const char* bpr = rb_cur + arow * RECROW + hi4 * 16;
        if constexpr (L == 0) { AF_LIST_20(AF_MFMA) }
        else                  { AF_LIST_32(AF_MFMA) }
        asm volatile("s_nop 7\n\ts_nop 7"
                     : "+v"(accA0), "+v"(accA1), "+v"(accB0), "+v"(accB1));
        f32x4 am0 = accA0 + accA1, am1 = accB0 + accB1;

        // ---- elementwise (2 units/lane: batch rows arow and 16+arow) ----
        float ig0 = sigm(am0[0]), fg0 = sigm(am0[1]);
        float gg0 = tanh_f(am0[2]), og0 = sigm(am0[3]);
        c0 = fg0 * c0 + ig0 * gg0;
        float h0f = og0 * tanh_f(c0);
        float ig1 = sigm(am1[0]), fg1 = sigm(am1[1]);
        float gg1 = tanh_f(am1[2]), og1 = sigm(am1[3]);
        c1 = fg1 * c1 + ig1 * gg1;
        float h1f = og1 * tanh_f(c1);
        int hv0 = f2bf(h0f), hv1 = f2bf(h1f);

        // own-slice h -> recb[par^1] (next step's rec)
        *(ushort*)(rb_nxt + arow * RECROW + (Uw + hi4) * 2)        = (ushort)hv0;
        *(ushort*)(rb_nxt + (16 + arow) * RECROW + (Uw + hi4) * 2) = (ushort)hv1;

        // ---- wave-major publish: two coalesced 128B segments per wave ----
        int a0 = __shfl(hv0, arow, 64),      a1 = __shfl(hv0, 16 + arow, 64);
        int a2 = __shfl(hv0, 32 + arow, 64), a3 = __shfl(hv0, 48 + arow, 64);
        int e0 = __shfl(hv1, arow, 64),      e1 = __shfl(hv1, 16 + arow, 64);
        int e2 = __shfl(hv1, 32 + arow, 64), e3 = __shfl(hv1, 48 + arow, 64);
        if (hi4 == 0) {
            unsigned lo0 = (a0 & 0xFFFF) | (a1 << 16);
            unsigned hi0 = (a2 & 0xFFFF) | (a3 << 16);
            unsigned long long pk0 = lo0 | ((unsigned long long)hi0 << 32);
            unsigned lo1 = (e0 & 0xFFFF) | (e1 << 16);
            unsigned hi1 = (e2 & 0xFFFF) | (e3 << 16);
            unsigned long long pk1 = lo1 | ((unsigned long long)hi1 << 32);
            ushort* chunk;
            if constexpr (L == 0)
                chunk = h0s + ((size_t)(t + 1)) * TSTR + ((size_t)tile * 16 + g) * 1024;
            else
                chunk = h1p + (((size_t)((t + 1) & 1) * 8 + tile) * 16 + g) * 1024;
            // wave-major: [wv w][row][4 units] -> ushort offset w*128 + row*4
            asm volatile("global_store_dwordx2 %0, %2, off sc0 sc1\n\t"
                         "global_store_dwordx2 %1, %3, off sc0 sc1"
                         :: "v"((unsigned long long)(chunk + w * 128 + arow * 4)),
                            "v"((unsigned long long)(chunk + w * 128 + (16 + arow) * 4)),
                            "v"(pk0), "v"(pk1) : "memory");
        }
        if (L == 1 && t == TSEQ - 1) {
            hlast[(size_t)(b0 + arow) * 512 + Uw + hi4]      = h0f;
            hlast[(size_t)(b0 + 16 + arow) * 512 + Uw + hi4] = h1f;
        }

        // ---- per-wave flag: own stores drained -> flag, NO barrier ----
        asm volatile("s_waitcnt vmcnt(0)" ::: "memory");
        if (lane == 0)
            asm volatile("global_store_dword %0, %1, off sc0 sc1"
                         :: "v"(myflagA), "v"(t + 1) : "memory");
    }
}

__global__ __attribute__((amdgpu_waves_per_eu(2, 2))) __launch_bounds__(512)
void lstm_fused(const float* __restrict__ x,
                const ushort* __restrict__ Wc0, const ushort* __restrict__ Wc1,
                const float* __restrict__ bg0, const float* __restrict__ bg1,
                ushort* __restrict__ h0s, ushort* __restrict__ h1p,
                float* __restrict__ hlast, int* flags)
{
    __shared__ __align__(16) char smem[135168];   // 2x33792 recb + 2x33792 inb; >80KiB -> 1 block/CU
    const int bid = blockIdx.x;
    if (bid < 128) lstm_body<0>(smem, bid, x, Wc0, bg0, h0s, h1p, hlast, flags);
    else           lstm_body<1>(smem, bid, x, Wc1, bg1, h0s, h1p, hlast, flags);
}

__global__ void fc_kernel(const float* __restrict__ hlast, const float* __restrict__ Wfc,
                          const float* __restrict__ bfc, float* __restrict__ out) {
    __shared__ float hs[HIDDEN];
    const int b = blockIdx.x, n = threadIdx.x;   // 128 threads
    for (int k = n; k < HIDDEN; k += 128) hs[k] = hlast[b * HIDDEN + k];
    __syncthreads();
    const float* wr = Wfc + (long)n * HIDDEN;
    float acc = bfc[n];
#pragma unroll 8
    for (int k = 0; k < HIDDEN; ++k) acc += hs[k] * wr[k];
    out[b * 128 + n] = acc;
}

extern "C" void kernel_launch(void* const* d_in, const int* in_sizes, int n_in,
                              void* d_out, int out_size, void* d_ws, size_t ws_size,
                              hipStream_t stream) {
    const float* x    = (const float*)d_in[0];
    const float* Wih0 = (const float*)d_in[1];
    const float* Whh0 = (const float*)d_in[2];
    const float* bih0 = (const float*)d_in[3];
    const float* bhh0 = (const float*)d_in[4];
    const float* Wih1 = (const float*)d_in[5];
    const float* Whh1 = (const float*)d_in[6];
    const float* bih1 = (const float*)d_in[7];
    const float* bhh1 = (const float*)d_in[8];
    const float* Wfc  = (const float*)d_in[9];
    const float* bfc  = (const float*)d_in[10];

    char* ws = (char*)d_ws;
    size_t off = 0;
    auto alloc = [&](size_t bytes) {
        void* p = ws + off;
        off = (off + bytes + 255) & ~(size_t)255;
        return p;
    };
    ushort* Wc0   = (ushort*)alloc(2048UL * 640 * 2);         // 2.62 MB
    ushort* Wc1   = (ushort*)alloc(2048UL * 1024 * 2);        // 4.19 MB
    float*  bg0   = (float*)alloc(2048 * 4);
    float*  bg1   = (float*)alloc(2048 * 4);
    float*  hlast = (float*)alloc(256UL * 512 * 4);           // 0.52 MB
    ushort* h1p   = (ushort*)alloc(2UL * 128 * 1024 * 2);     // 0.52 MB
    int*    flags = (int*)alloc(262144);                      // 2 layers x 8 tiles x 128 slots x 128 B
    ushort* h0s   = (ushort*)alloc(513UL * 128 * 1024 * 2);   // 134.5 MB (wave-major chunks)
    if (ws_size < off) return;

    hipMemsetAsync(flags, 0, 262144, stream);
    init_zeros<<<256, 256, 0, stream>>>(h0s, h1p);
    cast_w<<<(2048 * 640  + 255) / 256, 256, 0, stream>>>(Wih0, Whh0, Wc0, 128, 640);
    cast_w<<<(2048 * 1024 + 255) / 256, 256, 0, stream>>>(Wih1, Whh1, Wc1, 512, 1024);
    prep_bias<<<8, 256, 0, stream>>>(bih0, bhh0, bih1, bhh1, bg0, bg1);

    {
        void* args[] = { (void*)&x, (void*)&Wc0, (void*)&Wc1, (void*)&bg0, (void*)&bg1,
                         (void*)&h0s, (void*)&h1p, (void*)&hlast, (void*)&flags };
        hipLaunchCooperativeKernel((const void*)lstm_fused, dim3(256), dim3(512),
                                   args, 0, stream);
    }

    fc_kernel<<<256, 128, 0, stream>>>(hlast, Wfc, bfc, (float*)d_out);
}

// Round 17
// 1858.583 us; speedup vs baseline: 1.3685x; 1.3685x over previous
//
#include <hip/hip_runtime.h>

#define HIDDEN 512
#define TSEQ 512
#define NKEYS 128

typedef short short8_t __attribute__((ext_vector_type(8)));
typedef short short4_t __attribute__((ext_vector_type(4)));
typedef float f32x4 __attribute__((ext_vector_type(4)));
typedef int i32x4 __attribute__((ext_vector_type(4)));

__device__ __forceinline__ ushort f2bf(float f) {
    union { float f; unsigned u; } v; v.f = f;
    unsigned r = (v.u + 0x7FFFu + ((v.u >> 16) & 1u)) >> 16;
    return (ushort)r;
}
__device__ __forceinline__ float sigm(float x) { return 1.0f / (1.0f + __expf(-x)); }
__device__ __forceinline__ float tanh_f(float x) { return 2.0f / (1.0f + __expf(-2.0f * x)) - 1.0f; }

// Plain row-major bf16 cast of [W_ih | W_hh]: Wc[row*K + k].
__global__ void cast_w(const float* __restrict__ Wih, const float* __restrict__ Whh,
                       ushort* __restrict__ Wc, int KIN, int K) {
    long idx = (long)blockIdx.x * blockDim.x + threadIdx.x;
    if (idx >= (long)2048 * K) return;
    int row = (int)(idx / K), k = (int)(idx % K);
    float v = (k < KIN) ? Wih[(long)row * KIN + k] : Whh[(long)row * HIDDEN + (k - KIN)];
    Wc[idx] = f2bf(v);
}

__global__ void prep_bias(const float* __restrict__ a, const float* __restrict__ b,
                          const float* __restrict__ c, const float* __restrict__ d,
                          float* __restrict__ b0, float* __restrict__ b1) {
    int i = blockIdx.x * blockDim.x + threadIdx.x;
    if (i < 2048) { b0[i] = a[i] + b[i]; b1[i] = c[i] + d[i]; }
}

// Zero h0s slot 0 (h0(-1)) and h1p parity 0 (h1(-1)); both are 131072 ushorts.
__global__ void init_zeros(ushort* __restrict__ h0s, ushort* __restrict__ h1p) {
    int idx = blockIdx.x * blockDim.x + threadIdx.x;   // 65536 threads, ushort4 each
    ushort4 z = {0, 0, 0, 0};
    if (idx < 32768) *(ushort4*)(h0s + (size_t)idx * 4) = z;
    else             *(ushort4*)(h1p + (size_t)(idx - 32768) * 4) = z;
}

// ---- named weight registers, pinned into AGPRs ----
#define AF_LIST_20(M) M(0)M(1)M(2)M(3)M(4)M(5)M(6)M(7)M(8)M(9)M(10)M(11)M(12)M(13)M(14)M(15)M(16)M(17)M(18)M(19)
#define AF_LIST_32(M) AF_LIST_20(M) M(20)M(21)M(22)M(23)M(24)M(25)M(26)M(27)M(28)M(29)M(30)M(31)

#define AF_DECL(i) short8_t af##i;
#define AF_LOAD(i) af##i = *(const short8_t*)(wsrc + (i) * 32); \
                   asm volatile("" : "+a"(af##i));

// Two M-subtiles (batch rows arow and 16+arow) share each weight fragment.
#define AF_MFMA(i) { \
    const char* _b  = ((i) < KSI) ? (bpi + (i) * 64) : (bpr + ((i) - KSI) * 64); \
    const int   _r16 = ((i) < KSI) ? (16 * INROW) : (16 * RECROW); \
    short8_t bf0 = *(const short8_t*)_b; \
    short8_t bf1 = *(const short8_t*)(_b + _r16); \
    if ((i) & 1) { \
        asm("v_mfma_f32_16x16x32_bf16 %0, %1, %2, %0" : "+v"(accA1) : "a"(af##i), "v"(bf0)); \
        asm("v_mfma_f32_16x16x32_bf16 %0, %1, %2, %0" : "+v"(accB1) : "a"(af##i), "v"(bf1)); \
    } else { \
        asm("v_mfma_f32_16x16x32_bf16 %0, %1, %2, %0" : "+v"(accA0) : "a"(af##i), "v"(bf0)); \
        asm("v_mfma_f32_16x16x32_bf16 %0, %1, %2, %0" : "+v"(accB0) : "a"(af##i), "v"(bf1)); \
    } }

// Fused 2-layer LSTM, layer-pipelined, XCD-local. Round-17 = r15 EXACTLY except
// the arrival transport (r16 post-mortem: r15->r16 quadrupled polled flag lines
// and regressed 25%; poll-storm theory):
//   WAVE 0 polls the LLC flags (r15 per-lane poll, 16 r + 16 i lines/block)
//   and broadcasts arrivals via a 128B LDS arrived[] (monotone flag values).
//   WAVES 1-7 spin on LDS (no LLC traffic) then issue their data loads.
//   LLC poll pressure drops 8x (~13.7 -> ~1.7 TB/s of sc0sc1 line-touches).
// Ordering: spinner's data load issues after LDS-observe > wave0 flag-observe
// > producer drain; LLC order is transitive. Everything else = r15.
template <int L>
__device__ __forceinline__ void lstm_body(
    char* smem, int bid,
    const float* __restrict__ x, const ushort* __restrict__ Wc,
    const float* __restrict__ biasc, ushort* __restrict__ h0s,
    ushort* __restrict__ h1p, float* __restrict__ hlast, int* flags)
{
    constexpr int KIN   = L ? 512 : 128;
    constexpr int K     = KIN + 512;
    constexpr int KSI   = KIN / 32;          // input-half k-steps (4 / 16)
    constexpr int INROW = L ? 1056 : 288;    // inb row stride (bytes), == 32 mod 128
    constexpr int RECROW = 1056;             // recb row stride (bytes)
    constexpr int RECPAR = 32 * RECROW;      // 33792 B per parity
    constexpr size_t TSTR = 128 * 1024;      // h0s t-slot stride (ushorts)

    char* const recb = smem;                 // 2 parities x 32 rows
    char* const inb  = smem + 2 * RECPAR;
    volatile int* const arrR = (volatile int*)(smem + 101376);  // [16] rec arrivals
    volatile int* const arrI = arrR + 16;                       // [16] input arrivals

    const int tid = threadIdx.x;
    const int tile = bid & 7;                // tile == XCD (bid%8 mapping)
    const int g    = (bid >> 3) & 15;
    const int b0   = tile * 32;
    const int w = tid >> 6, lane = tid & 63, hi4 = lane >> 4, arow = lane & 15;
    const int Uw = g * 32 + w * 4;
    const int row_l = 512 * (arow & 3) + Uw + (arow >> 2);

    int* const ownbase  = flags + (L ? 4096 : 0) + tile * 512;  // 16 slots x 128 B
    int* const prodbase = flags + tile * 512;                   // L0 slots (for L1)
    int* const myflag   = ownbase + g * 32;

    // ---- weights -> AGPRs (once) ----
    AF_LIST_32(AF_DECL)
    {
        const ushort* wsrc = Wc + (size_t)row_l * K + hi4 * 8;
        if constexpr (L == 0) { AF_LIST_20(AF_LOAD) }
        else                  { AF_LIST_32(AF_LOAD) }
    }
    f32x4 bias4;
#pragma unroll
    for (int r = 0; r < 4; ++r) bias4[r] = biasc[512 * r + Uw + hi4];

    // zero recb (own chunk of parity 0 must be 0 = h(-1)) + arrived[]
    for (int i = tid; i < 2 * RECPAR / 4; i += 512) ((int*)recb)[i] = 0;
    if (tid < 32) arrR[tid] = 0;

    float c0 = 0.0f, c1 = 0.0f;

    // x prefetch registers (L0): row si, 8 floats at sj*8
    const int si = tid >> 4, sj = tid & 15;
    float4 xa, xb;
    if constexpr (L == 0) {
        const float* xp = x + ((size_t)(b0 + si) * TSEQ) * NKEYS + sj * 8;
        xa = *(const float4*)xp; xb = *(const float4*)(xp + 4);
    }

    const int pub = lane >> 2, q = lane & 3;   // stage role: (producer, 16B quarter)
    const bool notown = pub != g;
    const unsigned long long rflagA = (unsigned long long)(ownbase + pub * 32);
    const unsigned long long iflagA = (unsigned long long)(prodbase + pub * 32);

    __syncthreads();   // recb + arrived zeroed

#pragma unroll 1
    for (int t = 0; t < TSEQ; ++t) {
        const int par = t & 1;
        char* const rb_cur = recb + par * RECPAR;
        char* const rb_nxt = recb + (par ^ 1) * RECPAR;

        // ---- x input -> inb (L0; prev step's compute done before B_f) ----
        if constexpr (L == 0) {
            short8_t s;
            s[0] = (short)f2bf(xa.x); s[1] = (short)f2bf(xa.y);
            s[2] = (short)f2bf(xa.z); s[3] = (short)f2bf(xa.w);
            s[4] = (short)f2bf(xb.x); s[5] = (short)f2bf(xb.y);
            s[6] = (short)f2bf(xb.z); s[7] = (short)f2bf(xb.w);
            *(short8_t*)(inb + si * INROW + sj * 16) = s;
        }

        // ---- arrival transport + early-load ----
        i32x4 i0, i1, i2, i3, r0, r1, r2, r3;
        {
            int ipend = (L == 1) ? 1 : 0;
            int rpend = notown ? 1 : 0;
            if (w == 0) {
                // wave 0: poll LLC flags (per-lane pub), mark LDS, early-load own role
                while (true) {
                    if (ipend) {
                        int v;
                        asm volatile("global_load_dword %0, %1, off sc0 sc1\n\t"
                                     "s_waitcnt vmcnt(0)"
                                     : "=&v"(v) : "v"(iflagA) : "memory");
                        if (v >= t + 1) {
                            arrI[pub] = v;
                            const ushort* p = h0s + ((size_t)(t + 1)) * TSTR
                                              + ((size_t)tile * 16 + pub) * 1024
                                              + (size_t)w * 128 + q * 8;
                            asm volatile("global_load_dwordx4 %0, %4, off\n\t"
                                         "global_load_dwordx4 %1, %5, off\n\t"
                                         "global_load_dwordx4 %2, %6, off\n\t"
                                         "global_load_dwordx4 %3, %7, off"
                                         : "=&v"(i0), "=&v"(i1), "=&v"(i2), "=&v"(i3)
                                         : "v"((unsigned long long)p),
                                           "v"((unsigned long long)(p + 32)),
                                           "v"((unsigned long long)(p + 64)),
                                           "v"((unsigned long long)(p + 96))
                                         : "memory");
                            ipend = 0;
                        }
                    }
                    if (rpend) {
                        int v;
                        asm volatile("global_load_dword %0, %1, off sc0 sc1\n\t"
                                     "s_waitcnt vmcnt(0)"
                                     : "=&v"(v) : "v"(rflagA) : "memory");
                        if (v >= t) {
                            arrR[pub] = v;
                            if constexpr (L == 0) {
                                const ushort* p = h0s + ((size_t)t) * TSTR
                                                  + ((size_t)tile * 16 + pub) * 1024
                                                  + (size_t)w * 128 + q * 8;
                                asm volatile("global_load_dwordx4 %0, %4, off\n\t"
                                             "global_load_dwordx4 %1, %5, off\n\t"
                                             "global_load_dwordx4 %2, %6, off\n\t"
                                             "global_load_dwordx4 %3, %7, off"
                                             : "=&v"(r0), "=&v"(r1), "=&v"(r2), "=&v"(r3)
                                             : "v"((unsigned long long)p),
                                               "v"((unsigned long long)(p + 32)),
                                               "v"((unsigned long long)(p + 64)),
                                               "v"((unsigned long long)(p + 96))
                                             : "memory");
                            } else {
                                const ushort* p = h1p + (((size_t)par * 8 + tile) * 16 + pub) * 1024
                                                  + (size_t)w * 128 + q * 8;
                                asm volatile("global_load_dwordx4 %0, %4, off sc0 sc1\n\t"
                                             "global_load_dwordx4 %1, %5, off sc0 sc1\n\t"
                                             "global_load_dwordx4 %2, %6, off sc0 sc1\n\t"
                                             "global_load_dwordx4 %3, %7, off sc0 sc1"
                                             : "=&v"(r0), "=&v"(r1), "=&v"(r2), "=&v"(r3)
                                             : "v"((unsigned long long)p),
                                               "v"((unsigned long long)(p + 32)),
                                               "v"((unsigned long long)(p + 64)),
                                               "v"((unsigned long long)(p + 96))
                                             : "memory");
                            }
                            rpend = 0;
                        }
                    }
                    if (__all((ipend | rpend) == 0)) break;
                    __builtin_amdgcn_s_sleep(1);
                }
            } else {
                // waves 1-7: spin on LDS arrivals (no LLC traffic), then load
                if (ipend) {
                    while (arrI[pub] < t + 1) __builtin_amdgcn_s_sleep(0);
                    const ushort* p = h0s + ((size_t)(t + 1)) * TSTR
                                      + ((size_t)tile * 16 + pub) * 1024
                                      + (size_t)w * 128 + q * 8;
                    asm volatile("global_load_dwordx4 %0, %4, off\n\t"
                                 "global_load_dwordx4 %1, %5, off\n\t"
                                 "global_load_dwordx4 %2, %6, off\n\t"
                                 "global_load_dwordx4 %3, %7, off"
                                 : "=&v"(i0), "=&v"(i1), "=&v"(i2), "=&v"(i3)
                                 : "v"((unsigned long long)p),
                                   "v"((unsigned long long)(p + 32)),
                                   "v"((unsigned long long)(p + 64)),
                                   "v"((unsigned long long)(p + 96))
                                 : "memory");
                }
                if (rpend) {
                    while (arrR[pub] < t) __builtin_amdgcn_s_sleep(0);
                    if constexpr (L == 0) {
                        const ushort* p = h0s + ((size_t)t) * TSTR
                                          + ((size_t)tile * 16 + pub) * 1024
                                          + (size_t)w * 128 + q * 8;
                        asm volatile("global_load_dwordx4 %0, %4, off\n\t"
                                     "global_load_dwordx4 %1, %5, off\n\t"
                                     "global_load_dwordx4 %2, %6, off\n\t"
                                     "global_load_dwordx4 %3, %7, off"
                                     : "=&v"(r0), "=&v"(r1), "=&v"(r2), "=&v"(r3)
                                     : "v"((unsigned long long)p),
                                       "v"((unsigned long long)(p + 32)),
                                       "v"((unsigned long long)(p + 64)),
                                       "v"((unsigned long long)(p + 96))
                                     : "memory");
                    } else {
                        const ushort* p = h1p + (((size_t)par * 8 + tile) * 16 + pub) * 1024
                                          + (size_t)w * 128 + q * 8;
                        asm volatile("global_load_dwordx4 %0, %4, off sc0 sc1\n\t"
                                     "global_load_dwordx4 %1, %5, off sc0 sc1\n\t"
                                     "global_load_dwordx4 %2, %6, off sc0 sc1\n\t"
                                     "global_load_dwordx4 %3, %7, off sc0 sc1"
                                     : "=&v"(r0), "=&v"(r1), "=&v"(r2), "=&v"(r3)
                                     : "v"((unsigned long long)p),
                                       "v"((unsigned long long)(p + 32)),
                                       "v"((unsigned long long)(p + 64)),
                                       "v"((unsigned long long)(p + 96))
                                     : "memory");
                    }
                }
            }
            asm volatile("s_waitcnt vmcnt(0)" ::: "memory");
            if constexpr (L == 1) {
                *(i32x4*)(inb + (w * 4 + 0) * INROW + pub * 64 + q * 16) = i0;
                *(i32x4*)(inb + (w * 4 + 1) * INROW + pub * 64 + q * 16) = i1;
                *(i32x4*)(inb + (w * 4 + 2) * INROW + pub * 64 + q * 16) = i2;
                *(i32x4*)(inb + (w * 4 + 3) * INROW + pub * 64 + q * 16) = i3;
            }
            if (notown) {
                *(i32x4*)(rb_cur + (w * 4 + 0) * RECROW + pub * 64 + q * 16) = r0;
                *(i32x4*)(rb_cur + (w * 4 + 1) * RECROW + pub * 64 + q * 16) = r1;
                *(i32x4*)(rb_cur + (w * 4 + 2) * RECROW + pub * 64 + q * 16) = r2;
                *(i32x4*)(rb_cur + (w * 4 + 3) * RECROW + pub * 64 + q * 16) = r3;
            }
        }
        // x prefetch for t+1 (cached path; consumed next step)
        if constexpr (L == 0) {
            const int tt = (t + 1) & 511;
            const float* xp = x + ((size_t)(b0 + si) * TSEQ + tt) * NKEYS + sj * 8;
            xa = *(const float4*)xp; xb = *(const float4*)(xp + 4);
        }
        __syncthreads();   // B_s: all rows staged (own chunk already in LDS)

        // ---- MFMA sweep (A from AGPR, B from LDS; 2 subtiles x 2 chains) ----
        f32x4 accA0 = bias4, accB0 = bias4;
        f32x4 accA1 = {0.f, 0.f, 0.f, 0.f}, accB1 = {0.f, 0.f, 0.f, 0.f};
        const char* bpi = inb + arow * INROW + hi4 * 16;
        const char* bpr = rb_cur + arow * RECROW + hi4 * 16;
        if constexpr (L == 0) { AF_LIST_20(AF_MFMA) }
        else                  { AF_LIST_32(AF_MFMA) }
        asm volatile("s_nop 7\n\ts_nop 7"
                     : "+v"(accA0), "+v"(accA1), "+v"(accB0), "+v"(accB1));
        f32x4 am0 = accA0 + accA1, am1 = accB0 + accB1;

        // ---- elementwise (2 units/lane: batch rows arow and 16+arow) ----
        float ig0 = sigm(am0[0]), fg0 = sigm(am0[1]);
        float gg0 = tanh_f(am0[2]), og0 = sigm(am0[3]);
        c0 = fg0 * c0 + ig0 * gg0;
        float h0f = og0 * tanh_f(c0);
        float ig1 = sigm(am1[0]), fg1 = sigm(am1[1]);
        float gg1 = tanh_f(am1[2]), og1 = sigm(am1[3]);
        c1 = fg1 * c1 + ig1 * gg1;
        float h1f = og1 * tanh_f(c1);
        int hv0 = f2bf(h0f), hv1 = f2bf(h1f);

        // own-slice h -> recb[par^1] (next step's rec)
        *(ushort*)(rb_nxt + arow * RECROW + (Uw + hi4) * 2)        = (ushort)hv0;
        *(ushort*)(rb_nxt + (16 + arow) * RECROW + (Uw + hi4) * 2) = (ushort)hv1;

        // ---- direct publish from registers (publisher-major dst) ----
        int a0 = __shfl(hv0, arow, 64),      a1 = __shfl(hv0, 16 + arow, 64);
        int a2 = __shfl(hv0, 32 + arow, 64), a3 = __shfl(hv0, 48 + arow, 64);
        int e0 = __shfl(hv1, arow, 64),      e1 = __shfl(hv1, 16 + arow, 64);
        int e2 = __shfl(hv1, 32 + arow, 64), e3 = __shfl(hv1, 48 + arow, 64);
        if (hi4 == 0) {
            unsigned lo0 = (a0 & 0xFFFF) | (a1 << 16);
            unsigned hi0 = (a2 & 0xFFFF) | (a3 << 16);
            unsigned long long pk0 = lo0 | ((unsigned long long)hi0 << 32);
            unsigned lo1 = (e0 & 0xFFFF) | (e1 << 16);
            unsigned hi1 = (e2 & 0xFFFF) | (e3 << 16);
            unsigned long long pk1 = lo1 | ((unsigned long long)hi1 << 32);
            ushort* chunk;
            if constexpr (L == 0)
                chunk = h0s + ((size_t)(t + 1)) * TSTR + ((size_t)tile * 16 + g) * 1024;
            else
                chunk = h1p + (((size_t)((t + 1) & 1) * 8 + tile) * 16 + g) * 1024;
            asm volatile("global_store_dwordx2 %0, %2, off sc0 sc1\n\t"
                         "global_store_dwordx2 %1, %3, off sc0 sc1"
                         :: "v"((unsigned long long)(chunk + arow * 32 + w * 4)),
                            "v"((unsigned long long)(chunk + (16 + arow) * 32 + w * 4)),
                            "v"(pk0), "v"(pk1) : "memory");
        }
        if (L == 1 && t == TSEQ - 1) {
            hlast[(size_t)(b0 + arow) * 512 + Uw + hi4]      = h0f;
            hlast[(size_t)(b0 + 16 + arow) * 512 + Uw + hi4] = h1f;
        }

        asm volatile("s_waitcnt vmcnt(0)" ::: "memory");
        __syncthreads();   // B_f: all publishes at LLC, all LDS writes done
        if (tid == 0)
            asm volatile("global_store_dword %0, %1, off sc0 sc1"
                         :: "v"((unsigned long long)myflag), "v"(t + 1) : "memory");
    }
}

__global__ __attribute__((amdgpu_waves_per_eu(2, 2))) __launch_bounds__(512)
void lstm_fused(const float* __restrict__ x,
                const ushort* __restrict__ Wc0, const ushort* __restrict__ Wc1,
                const float* __restrict__ bg0, const float* __restrict__ bg1,
                ushort* __restrict__ h0s, ushort* __restrict__ h1p,
                float* __restrict__ hlast, int* flags)
{
    __shared__ __align__(16) char smem[101504];   // recb 2x33792 + inb 33792 + arrived 128; >80KiB -> 1 block/CU
    const int bid = blockIdx.x;
    if (bid < 128) lstm_body<0>(smem, bid, x, Wc0, bg0, h0s, h1p, hlast, flags);
    else           lstm_body<1>(smem, bid, x, Wc1, bg1, h0s, h1p, hlast, flags);
}

__global__ void fc_kernel(const float* __restrict__ hlast, const float* __restrict__ Wfc,
                          const float* __restrict__ bfc, float* __restrict__ out) {
    __shared__ float hs[HIDDEN];
    const int b = blockIdx.x, n = threadIdx.x;   // 128 threads
    for (int k = n; k < HIDDEN; k += 128) hs[k] = hlast[b * HIDDEN + k];
    __syncthreads();
    const float* wr = Wfc + (long)n * HIDDEN;
    float acc = bfc[n];
#pragma unroll 8
    for (int k = 0; k < HIDDEN; ++k) acc += hs[k] * wr[k];
    out[b * 128 + n] = acc;
}

extern "C" void kernel_launch(void* const* d_in, const int* in_sizes, int n_in,
                              void* d_out, int out_size, void* d_ws, size_t ws_size,
                              hipStream_t stream) {
    const float* x    = (const float*)d_in[0];
    const float* Wih0 = (const float*)d_in[1];
    const float* Whh0 = (const float*)d_in[2];
    const float* bih0 = (const float*)d_in[3];
    const float* bhh0 = (const float*)d_in[4];
    const float* Wih1 = (const float*)d_in[5];
    const float* Whh1 = (const float*)d_in[6];
    const float* bih1 = (const float*)d_in[7];
    const float* bhh1 = (const float*)d_in[8];
    const float* Wfc  = (const float*)d_in[9];
    const float* bfc  = (const float*)d_in[10];

    char* ws = (char*)d_ws;
    size_t off = 0;
    auto alloc = [&](size_t bytes) {
        void* p = ws + off;
        off = (off + bytes + 255) & ~(size_t)255;
        return p;
    };
    ushort* Wc0   = (ushort*)alloc(2048UL * 640 * 2);         // 2.62 MB
    ushort* Wc1   = (ushort*)alloc(2048UL * 1024 * 2);        // 4.19 MB
    float*  bg0   = (float*)alloc(2048 * 4);
    float*  bg1   = (float*)alloc(2048 * 4);
    float*  hlast = (float*)alloc(256UL * 512 * 4);           // 0.52 MB
    ushort* h1p   = (ushort*)alloc(2UL * 128 * 1024 * 2);     // 0.52 MB
    int*    flags = (int*)alloc(65536);                       // 2 layers x 8 tiles x 16 slots x 128 B
    ushort* h0s   = (ushort*)alloc(513UL * 128 * 1024 * 2);   // 134.5 MB (publisher-major)
    if (ws_size < off) return;

    hipMemsetAsync(flags, 0, 65536, stream);
    init_zeros<<<256, 256, 0, stream>>>(h0s, h1p);
    cast_w<<<(2048 * 640  + 255) / 256, 256, 0, stream>>>(Wih0, Whh0, Wc0, 128, 640);
    cast_w<<<(2048 * 1024 + 255) / 256, 256, 0, stream>>>(Wih1, Whh1, Wc1, 512, 1024);
    prep_bias<<<8, 256, 0, stream>>>(bih0, bhh0, bih1, bhh1, bg0, bg1);

    {
        void* args[] = { (void*)&x, (void*)&Wc0, (void*)&Wc1, (void*)&bg0, (void*)&bg1,
                         (void*)&h0s, (void*)&h1p, (void*)&hlast, (void*)&flags };
        hipLaunchCooperativeKernel((const void*)lstm_fused, dim3(256), dim3(512),
                                   args, 0, stream);
    }

    fc_kernel<<<256, 128, 0, stream>>>(hlast, Wfc, bfc, (float*)d_out);
}